// Round 1
// baseline (274.787 us; speedup 1.0000x reference)
//
#include <hip/hip_runtime.h>
#include <math.h>

#define N_LAYERS 101

// Prepass (1 thread): collapse 101 x relu(h*w+b) into F(t) = max(A*t + B, C).
// Valid because max(A*t+B, C) is closed under h -> max(w*h + b, 0) when w >= 0:
//   max(w*max(At+B,C)+b, 0) = max(wA*t + wB+b, max(wC+b, 0)).
// Layer 0 needs no sign condition (h1 = max(w0*t+b0, 0) is already the form).
__global__ void collapse_abc(const float* __restrict__ w,
                             const float* __restrict__ b,
                             float* __restrict__ abc) {
    float A = w[0];
    float B = b[0];
    float C = 0.0f;
    float ok = 1.0f;
    for (int i = 1; i < N_LAYERS; ++i) {
        const float wi = w[i], bi = b[i];
        if (wi < 0.0f) ok = 0.0f;            // collapse invalid -> fallback
        A = wi * A;
        B = fmaf(wi, B, bi);
        C = fmaxf(fmaf(wi, C, bi), 0.0f);
    }
    abc[0] = A;
    abc[1] = B;
    abc[2] = C;
    abc[3] = ok;
}

__global__ __launch_bounds__(256) void fused_chain(
    const float4* __restrict__ x4,
    const float* __restrict__ x,        // scalar view for tail
    const float* __restrict__ w,
    const float* __restrict__ b,
    const float* __restrict__ abc,
    float4* __restrict__ o4,
    float* __restrict__ o,
    int n4, int n) {
    const float A = abc[0], B = abc[1], C = abc[2];
    const bool fast = (abc[3] != 0.0f);   // wave-uniform
    const int tid = blockIdx.x * blockDim.x + threadIdx.x;
    const int stride = gridDim.x * blockDim.x;

    if (fast) {
        for (int i = tid; i < n4; i += stride) {
            float4 v = x4[i];
            v.x = fmaxf(fmaf(A, v.x, B), C);
            v.y = fmaxf(fmaf(A, v.y, B), C);
            v.z = fmaxf(fmaf(A, v.z, B), C);
            v.w = fmaxf(fmaf(A, v.w, B), C);
            o4[i] = v;
        }
        // tail (n not divisible by 4) — no-op for this problem (n = 2^25)
        for (int i = n4 * 4 + tid; i < n; i += stride) {
            o[i] = fmaxf(fmaf(A, x[i], B), C);
        }
    } else {
        // Exact fallback: full 101-layer chain, w/b staged in LDS.
        __shared__ float ws[N_LAYERS];
        __shared__ float bs[N_LAYERS];
        for (int i = threadIdx.x; i < N_LAYERS; i += blockDim.x) {
            ws[i] = w[i];
            bs[i] = b[i];
        }
        __syncthreads();
        for (int i = tid; i < n4; i += stride) {
            float4 v = x4[i];
            for (int l = 0; l < N_LAYERS; ++l) {
                const float wl = ws[l], bl = bs[l];
                v.x = fmaxf(fmaf(wl, v.x, bl), 0.0f);
                v.y = fmaxf(fmaf(wl, v.y, bl), 0.0f);
                v.z = fmaxf(fmaf(wl, v.z, bl), 0.0f);
                v.w = fmaxf(fmaf(wl, v.w, bl), 0.0f);
            }
            o4[i] = v;
        }
        for (int i = n4 * 4 + tid; i < n; i += stride) {
            float v = x[i];
            for (int l = 0; l < N_LAYERS; ++l) {
                v = fmaxf(fmaf(ws[l], v, bs[l]), 0.0f);
            }
            o[i] = v;
        }
    }
}

extern "C" void kernel_launch(void* const* d_in, const int* in_sizes, int n_in,
                              void* d_out, int out_size, void* d_ws, size_t ws_size,
                              hipStream_t stream) {
    const float* x = (const float*)d_in[0];
    const float* w = (const float*)d_in[1];
    const float* b = (const float*)d_in[2];
    float* out = (float*)d_out;
    float* abc = (float*)d_ws;            // 4 floats of scratch

    const int n  = in_sizes[0];
    const int n4 = n / 4;

    collapse_abc<<<1, 1, 0, stream>>>(w, b, abc);

    // Memory-bound: cap grid at ~2048 blocks, grid-stride the rest.
    int blocks = (n4 + 255) / 256;
    if (blocks > 2048) blocks = 2048;
    fused_chain<<<blocks, 256, 0, stream>>>(
        (const float4*)x, x, w, b, abc, (float4*)out, out, n4, n);
}

// Round 2
// 237.706 us; speedup vs baseline: 1.1560x; 1.1560x over previous
//
#include <hip/hip_runtime.h>
#include <math.h>

#define N_LAYERS 101

// Single kernel. Collapses 101 x relu(h*w+b) into F(t) = max(A*t + B, C),
// valid when w_i >= 0 for i >= 1 (max(At+B,C) is closed under
// h -> max(w*h+b, 0) for w >= 0):
//   max(w*max(At+B,C)+b, 0) = max(wA*t + wB+b, max(wC+b, 0)).
// The collapse runs per-thread from LDS (~300 VALU ops, one-time) so there is
// no serial prepass kernel with unhidden global-load latency.
__global__ __launch_bounds__(256) void fused_chain(
    const float4* __restrict__ x4,
    const float* __restrict__ x,        // scalar view for tail
    const float* __restrict__ w,
    const float* __restrict__ b,
    float4* __restrict__ o4,
    float* __restrict__ o,
    int n4, int n) {
    __shared__ float ws[N_LAYERS];
    __shared__ float bs[N_LAYERS];
    for (int i = threadIdx.x; i < N_LAYERS; i += blockDim.x) {
        ws[i] = w[i];
        bs[i] = b[i];
    }
    __syncthreads();

    // Per-thread collapse from LDS. All threads compute identical values;
    // the branch below is uniform.
    float A = ws[0], B = bs[0], C = 0.0f;
    bool ok = true;
    for (int i = 1; i < N_LAYERS; ++i) {
        const float wi = ws[i], bi = bs[i];
        ok = ok && (wi >= 0.0f);
        A = wi * A;
        B = fmaf(wi, B, bi);
        C = fmaxf(fmaf(wi, C, bi), 0.0f);
    }

    const int tid = blockIdx.x * blockDim.x + threadIdx.x;
    const int stride = gridDim.x * blockDim.x;

    if (ok) {
        // Fast path: 1 FMA + 1 max per element, pure streaming.
        for (int i = tid; i < n4; i += stride) {
            float4 v = x4[i];
            v.x = fmaxf(fmaf(A, v.x, B), C);
            v.y = fmaxf(fmaf(A, v.y, B), C);
            v.z = fmaxf(fmaf(A, v.z, B), C);
            v.w = fmaxf(fmaf(A, v.w, B), C);
            o4[i] = v;
        }
        for (int i = n4 * 4 + tid; i < n; i += stride) {
            o[i] = fmaxf(fmaf(A, x[i], B), C);
        }
    } else {
        // Exact fallback (never taken for these inputs). unroll 1 keeps the
        // 101-deep loop from being unrolled and blowing up VGPR allocation
        // for the whole kernel.
        #pragma unroll 1
        for (int i = tid; i < n4; i += stride) {
            float4 v = x4[i];
            #pragma unroll 1
            for (int l = 0; l < N_LAYERS; ++l) {
                const float wl = ws[l], bl = bs[l];
                v.x = fmaxf(fmaf(wl, v.x, bl), 0.0f);
                v.y = fmaxf(fmaf(wl, v.y, bl), 0.0f);
                v.z = fmaxf(fmaf(wl, v.z, bl), 0.0f);
                v.w = fmaxf(fmaf(wl, v.w, bl), 0.0f);
            }
            o4[i] = v;
        }
        #pragma unroll 1
        for (int i = n4 * 4 + tid; i < n; i += stride) {
            float v = x[i];
            #pragma unroll 1
            for (int l = 0; l < N_LAYERS; ++l) {
                v = fmaxf(fmaf(ws[l], v, bs[l]), 0.0f);
            }
            o[i] = v;
        }
    }
}

extern "C" void kernel_launch(void* const* d_in, const int* in_sizes, int n_in,
                              void* d_out, int out_size, void* d_ws, size_t ws_size,
                              hipStream_t stream) {
    const float* x = (const float*)d_in[0];
    const float* w = (const float*)d_in[1];
    const float* b = (const float*)d_in[2];
    float* out = (float*)d_out;

    const int n  = in_sizes[0];
    const int n4 = n / 4;

    // Memory-bound: ~2048 blocks (8 blocks/CU), grid-stride the rest.
    int blocks = (n4 + 255) / 256;
    if (blocks > 2048) blocks = 2048;
    fused_chain<<<blocks, 256, 0, stream>>>(
        (const float4*)x, x, w, b, (float4*)out, out, n4, n);
}